// Round 10
// baseline (2239.856 us; speedup 1.0000x reference)
//
#include <hip/hip_runtime.h>
#include <math.h>

#define BSZ 8
#define SEQ 512
#define DM 256
#define NH 8
#define DH 32
#define DSTR 30
#define TQ 8
#define TK 64
#define NKT (SEQ / TK)
#define NIT (NKT * 4)

// ---------------------------------------------------------------------------
// Kernel 1: Q/K/V projections. out[b][h][l][d] layout; q pre-scaled 1/sqrt(32)
// grid (256, 3), block 256. 16 rows per block staged in LDS (3 blocks/CU).
// ---------------------------------------------------------------------------
__global__ __launch_bounds__(256, 8) void proj_kernel(
    const float* __restrict__ q_in, const float* __restrict__ k_in,
    const float* __restrict__ v_in,
    const float* __restrict__ wq, const float* __restrict__ bq,
    const float* __restrict__ wk, const float* __restrict__ bk,
    const float* __restrict__ wv, const float* __restrict__ bv,
    float* __restrict__ q_ws, float* __restrict__ k_ws, float* __restrict__ v_ws)
{
    __shared__ __align__(16) float a_lds[16][DM];
    const int t = threadIdx.x;
    const int z = blockIdx.y;
    const int row0 = blockIdx.x * 16;

    const float* in; const float* W; const float* bias; float* outp; float scale;
    if (z == 0)      { in = q_in; W = wq; bias = bq; outp = q_ws; scale = 0.17677669529663687f; }
    else if (z == 1) { in = k_in; W = wk; bias = bk; outp = k_ws; scale = 1.0f; }
    else             { in = v_in; W = wv; bias = bv; outp = v_ws; scale = 1.0f; }

    {
        const float4* src = (const float4*)(in + row0 * DM);
        float4* dst = (float4*)&a_lds[0][0];
#pragma unroll
        for (int j = 0; j < 4; ++j) dst[t + 256 * j] = src[t + 256 * j];
    }
    __syncthreads();

    const int n = t;
    float acc[16];
#pragma unroll
    for (int r = 0; r < 16; ++r) acc[r] = 0.f;
#pragma unroll 4
    for (int kk = 0; kk < DM; ++kk) {
        const float w = W[kk * DM + n];
#pragma unroll
        for (int r = 0; r < 16; ++r) acc[r] += a_lds[r][kk] * w;
    }
    const float bb = bias[n];
    const int h = n >> 5, d = n & 31;
#pragma unroll
    for (int r = 0; r < 16; ++r) {
        const int R = row0 + r; const int b = R >> 9, l = R & 511;
        outp[(((b * NH + h) * SEQ) + l) * DH + d] = (acc[r] + bb) * scale;
    }
}

// ---------------------------------------------------------------------------
// Kernel 2: fused structure-biased flash attention + output projection.
// grid (64, 8) [x: q-tile of 8 rows, y: batch], block 512 (8 waves, 2 blk/CU).
// Iteration it = kt*4 + pp handles q-pair (2pp, 2pp+1) of k-tile kt.
// Structure tiles are register-prefetched one iteration ahead (T14 pattern):
// HBM latency hides under the ~2700-FMA compute of the previous iteration.
// ---------------------------------------------------------------------------
__global__ __launch_bounds__(512, 4) void attn_kernel(
    const float* __restrict__ q_ws, const float* __restrict__ k_ws,
    const float* __restrict__ v_ws,
    const float* __restrict__ structure, const int* __restrict__ kmask,
    const float* __restrict__ wsk, const float* __restrict__ bsk,
    const float* __restrict__ wsv, const float* __restrict__ bsv,
    const float* __restrict__ wf,  const float* __restrict__ bf,
    float* __restrict__ out, float* __restrict__ s0_ws,
    float* __restrict__ m0_ws, float* __restrict__ l0_ws)
{
    __shared__ __align__(16) float st[2][TK * DSTR];  // flat 2x1920, no padding
    __shared__ float skv2[2][TK][64];   // [q-parity][k][swizzled col]; col<32: sk, col>=32: sv
    __shared__ float q_lds[TQ][NH][DH];
    __shared__ float p_lds[TQ][NH][TK];
    __shared__ float fac_lds[TQ][NH];
    __shared__ float m_lds[TQ][NH];
    __shared__ float l_lds[TQ][NH];

    const int t    = threadIdx.x;
    const int wave = t >> 6;          // score phase: wave == head; build: k-row group
    const int lane = t & 63;          // score phase: lane == k within tile; build: col
    const int b  = blockIdx.y;
    const int q0 = blockIdx.x * TQ;

    const int col = lane;             // build-phase output column (0..31 sk, 32..63 sv)
    const int kr  = wave;
    const int h2 = (t >> 5) & 7, dd = t & 31, qh = t >> 8;  // ctx-phase roles

    // wsk|wsv column held in registers (30 per thread), plus bias
    float wreg[DSTR];
#pragma unroll
    for (int s = 0; s < DSTR; ++s)
        wreg[s] = (col < 32) ? wsk[s * DH + col] : wsv[s * DH + (col - 32)];
    const float breg = (col < 32) ? bsk[col] : bsv[col - 32];

    if (t < TQ * NH) { ((float*)m_lds)[t] = -1e30f; ((float*)l_lds)[t] = 0.f; }
    for (int i = t; i < TQ * DM; i += 512) {
        const int q = i >> 8, c = i & 255, h = c >> 5, d = c & 31;
        q_lds[q][h][d] = q_ws[(((b * NH + h) * SEQ) + q0 + q) * DH + d];
    }
    float ctx[4] = {0.f, 0.f, 0.f, 0.f};

    // ---- prefetch structure tiles for it=0 into registers ----
    // per iteration: 2 q-rows x 64 k x 30 = 3840 floats = 960 float4
    float4 r0 = {0.f,0.f,0.f,0.f}, r1 = {0.f,0.f,0.f,0.f};
    {
        const float4* f0 = (const float4*)&structure[((size_t)(b * SEQ + q0 + 0) * SEQ + 0) * DSTR];
        const float4* f1 = (const float4*)&structure[((size_t)(b * SEQ + q0 + 1) * SEQ + 0) * DSTR];
        r0 = (t < 480) ? f0[t] : f1[t - 480];
        if (t < 448) r1 = f1[t + 32];
    }

    float Kreg[DH];
    bool masked = false;

    for (int it = 0; it < NIT; ++it) {
        const int kt = it >> 2, pp = it & 3;
        const int k0 = kt * TK;

        __syncthreads();                    // prev build done with st; prev ctx done with skv2
        {                                   // regs -> LDS (contiguous b128, conflict-free)
            float4* stf4 = (float4*)&st[0][0];
            stf4[t] = r0;
            if (t < 448) stf4[t + 512] = r1;
        }
        if (it + 1 < NIT) {                 // issue next tile's loads; consumed next iteration
            const int kt2 = (it + 1) >> 2, pp2 = (it + 1) & 3;
            const float4* f0 = (const float4*)&structure[((size_t)(b * SEQ + q0 + 2 * pp2    ) * SEQ + kt2 * TK) * DSTR];
            const float4* f1 = (const float4*)&structure[((size_t)(b * SEQ + q0 + 2 * pp2 + 1) * SEQ + kt2 * TK) * DSTR];
            r0 = (t < 480) ? f0[t] : f1[t - 480];
            if (t < 448) r1 = f1[t + 32];
        }
        if (pp == 0) {                      // new k-tile: K rows + mask (wave=h, lane=k)
            const float4* kp = (const float4*)&k_ws[(((b * NH + wave) * SEQ) + k0 + lane) * DH];
#pragma unroll
            for (int i = 0; i < 8; ++i) {
                const float4 f = kp[i];
                Kreg[4*i] = f.x; Kreg[4*i+1] = f.y; Kreg[4*i+2] = f.z; Kreg[4*i+3] = f.w;
            }
            masked = (kmask[b * SEQ + k0 + lane] != 0);
        }
        __syncthreads();                    // st ready

        // ---- build skv2 for both q-parities (reads st via wave-uniform b128) ----
#pragma unroll
        for (int sub = 0; sub < 2; ++sub) {
#pragma unroll
            for (int i = 0; i < 8; i += 2) {
                const int krow = kr * 8 + i;
                const float4* ap = (const float4*)&st[sub][krow * DSTR];  // 15 f4 = rows krow, krow+1
                float acc0 = breg, acc1 = breg;
#pragma unroll
                for (int u = 0; u < 7; ++u) {
                    const float4 x = ap[u];
                    acc0 += x.x*wreg[4*u] + x.y*wreg[4*u+1] + x.z*wreg[4*u+2] + x.w*wreg[4*u+3];
                }
                {
                    const float4 x = ap[7];    // seam: s=28,29 of row0 | s=0,1 of row1
                    acc0 += x.x*wreg[28] + x.y*wreg[29];
                    acc1 += x.z*wreg[0]  + x.w*wreg[1];
                }
#pragma unroll
                for (int u = 8; u < 15; ++u) {
                    const float4 x = ap[u];
                    const int sb = 4*u - 30;
                    acc1 += x.x*wreg[sb] + x.y*wreg[sb+1] + x.z*wreg[sb+2] + x.w*wreg[sb+3];
                }
                skv2[sub][krow    ][(col + krow    ) & 63] = acc0;  // swizzled store
                skv2[sub][krow + 1][(col + krow + 1) & 63] = acc1;
            }
        }
        __syncthreads();                    // skv2 ready

        // ---- scores + online softmax for the q-pair (wave=h, lane=k) ----
        {
            const int h = wave;
#pragma unroll
            for (int sub = 0; sub < 2; ++sub) {
                const int q = pp * 2 + sub;
                float s = 0.f;
#pragma unroll
                for (int d = 0; d < DH; ++d)
                    s += q_lds[q][h][d] * (Kreg[d] + skv2[sub][lane][(d + lane) & 63]);
                if (masked) s = -1e18f;
                if (h == 0) s0_ws[(size_t)(b * SEQ + q0 + q) * SEQ + k0 + lane] = s;

                float mt = s;
#pragma unroll
                for (int off = 32; off > 0; off >>= 1) mt = fmaxf(mt, __shfl_xor(mt, off));
                const float mold = m_lds[q][h];
                const float mnew = fmaxf(mold, mt);
                const float p = __expf(s - mnew);
                float ps = p;
#pragma unroll
                for (int off = 32; off > 0; off >>= 1) ps += __shfl_xor(ps, off);
                if (lane == 0) {
                    const float fac = __expf(mold - mnew);
                    m_lds[q][h] = mnew;
                    l_lds[q][h] = l_lds[q][h] * fac + ps;
                    fac_lds[q][h] = fac;
                }
                p_lds[q][h][lane] = p;
            }
        }
        __syncthreads();                    // p, fac ready

        // ---- rescale ctx + accumulate p * sv for this q-pair ----
        {
            const int q = pp * 2 + qh;
            const float fac = fac_lds[q][h2];
            float c = ctx[pp] * fac;
#pragma unroll
            for (int k = 0; k < TK; ++k)
                c += p_lds[q][h2][k] * skv2[qh][k][(32 + dd + k) & 63];
            ctx[pp] = c;
        }
        // ---- accumulate p * V once per k-tile (V is q-independent) ----
        if (pp == 3) {
            const float* vbase = &v_ws[((b * NH + h2) * SEQ + k0) * DH + dd];
#pragma unroll 8
            for (int k = 0; k < TK; ++k) {
                const float v = vbase[k * DH];
#pragma unroll
                for (int j = 0; j < 4; ++j)
                    ctx[j] += p_lds[2 * j + qh][h2][k] * v;
            }
        }
    }
    __syncthreads();
    // ---- normalize, park context in LDS (alias p_lds), dump h=0 m/l ----
    float* ctx_lds = &p_lds[0][0][0];       // needs TQ*256 floats; p_lds has TQ*512
#pragma unroll
    for (int j = 0; j < 4; ++j) {
        const int q = 2 * j + qh;
        ctx_lds[q * DM + h2 * DH + dd] = ctx[j] / l_lds[q][h2];
    }
    if (t < TQ) {
        m0_ws[b * SEQ + q0 + t] = m_lds[t][0];
        l0_ws[b * SEQ + q0 + t] = l_lds[t][0];
    }
    __syncthreads();
    // ---- output projection: context @ wf + bf ----
    {
        const int n = t & 255, qh2 = t >> 8;
        float acc[4] = {0.f, 0.f, 0.f, 0.f};
        for (int m = 0; m < DM; ++m) {
            const float w = wf[m * DM + n];
#pragma unroll
            for (int j = 0; j < 4; ++j) acc[j] += ctx_lds[(qh2 * 4 + j) * DM + m] * w;
        }
        const float bb = bf[n];
#pragma unroll
        for (int j = 0; j < 4; ++j) {
            const int q = qh2 * 4 + j;
            out[(size_t)(b * SEQ + q0 + q) * DM + n] = acc[j] + bb;
        }
    }
}

// ---------------------------------------------------------------------------
// Kernel 3: fin_attn = exp(score0 - m0) / l0   (head 0 attention rows)
// ---------------------------------------------------------------------------
__global__ void finattn_kernel(const float* __restrict__ s0_ws,
                               const float* __restrict__ m0_ws,
                               const float* __restrict__ l0_ws,
                               float* __restrict__ fin)
{
    const int row = blockIdx.x;
    const float m0 = m0_ws[row];
    const float inv_l = 1.0f / l0_ws[row];
    const int t = threadIdx.x;
#pragma unroll
    for (int k = t; k < SEQ; k += 256)
        fin[(size_t)row * SEQ + k] = __expf(s0_ws[(size_t)row * SEQ + k] - m0) * inv_l;
}

// ---------------------------------------------------------------------------
extern "C" void kernel_launch(void* const* d_in, const int* in_sizes, int n_in,
                              void* d_out, int out_size, void* d_ws, size_t ws_size,
                              hipStream_t stream)
{
    const float* keyp    = (const float*)d_in[0];
    const float* valp    = (const float*)d_in[1];
    const float* qryp    = (const float*)d_in[2];
    const float* structp = (const float*)d_in[3];
    const int*   maskp   = (const int*)d_in[4];   // bool input staged as int32
    const float* wq = (const float*)d_in[5];
    const float* bq = (const float*)d_in[6];
    const float* wk = (const float*)d_in[7];
    const float* bk = (const float*)d_in[8];
    const float* wv = (const float*)d_in[9];
    const float* bv = (const float*)d_in[10];
    const float* wsk = (const float*)d_in[11];
    const float* bsk = (const float*)d_in[12];
    const float* wsv = (const float*)d_in[13];
    const float* bsv = (const float*)d_in[14];
    const float* wf = (const float*)d_in[15];
    const float* bf = (const float*)d_in[16];

    float* ws    = (float*)d_ws;
    float* q_ws  = ws;                       // 4096*256
    float* k_ws  = q_ws + 1048576;           // 4096*256
    float* v_ws  = k_ws + 1048576;           // 4096*256
    float* s0_ws = v_ws + 1048576;           // 4096*512
    float* m0_ws = s0_ws + 2097152;          // 4096
    float* l0_ws = m0_ws + 4096;             // 4096

    float* outp = (float*)d_out;             // (8,512,256)
    float* finp = outp + 1048576;            // (8,512,512)

    dim3 pg(256, 3);
    proj_kernel<<<pg, 256, 0, stream>>>(qryp, keyp, valp, wq, bq, wk, bk, wv, bv,
                                        q_ws, k_ws, v_ws);
    dim3 ag(64, 8);
    attn_kernel<<<ag, 512, 0, stream>>>(q_ws, k_ws, v_ws, structp, maskp,
                                        wsk, bsk, wsv, bsv, wf, bf,
                                        outp, s0_ws, m0_ws, l0_ws);
    finattn_kernel<<<4096, 256, 0, stream>>>(s0_ws, m0_ws, l0_ws, finp);
}